// Round 1
// baseline (178.054 us; speedup 1.0000x reference)
//
#include <hip/hip_runtime.h>
#include <hip/hip_bf16.h>
#include <stdint.h>

using bf16 = __hip_bfloat16;
typedef __attribute__((ext_vector_type(8))) __bf16 bf16x8;
typedef __attribute__((ext_vector_type(4))) float f32x4;

// ---------------- cast fp32 -> bf16, 4 elems/thread ----------------
__global__ __launch_bounds__(256) void cast4_kernel(const float* __restrict__ in,
                                                    bf16* __restrict__ out) {
    const size_t i = ((size_t)blockIdx.x * 256 + threadIdx.x) * 4;
    const float4 v = *(const float4*)(in + i);
    bf16 h0 = __float2bfloat16(v.x), h1 = __float2bfloat16(v.y);
    bf16 h2 = __float2bfloat16(v.z), h3 = __float2bfloat16(v.w);
    uint2 u;
    u.x = (uint32_t)(*(const uint16_t*)&h0) | ((uint32_t)(*(const uint16_t*)&h1) << 16);
    u.y = (uint32_t)(*(const uint16_t*)&h2) | ((uint32_t)(*(const uint16_t*)&h3) << 16);
    *(uint2*)(out + i) = u;
}

// ---------------- C = A @ B^T (+bias), bf16 in, fp32 out ----------------
// A: M x K row-major bf16 ; B: N x K row-major bf16 (so C = A @ B^T)
// Writes C0 (fp32); optionally C1 (fp32 duplicate) and Cb (bf16 duplicate).
// m97 structure: 128x128 tile, BK=32, 4 waves (2x2), 16x16x32 bf16 MFMA,
// global_load_lds width-16 staging (wave-uniform LDS base + lane*16).
#define TM 128
#define TN 128
#define BK 32

__global__ __launch_bounds__(256) void gemm_bt(
    const bf16* __restrict__ A, const bf16* __restrict__ B,
    const float* __restrict__ bias,
    float* __restrict__ C0, float* __restrict__ C1, bf16* __restrict__ Cb,
    int M, int N, int K)
{
    __shared__ bf16 As[TM * BK];   // 8 KB, row-major [row][k], 64 B rows
    __shared__ bf16 Bs[TN * BK];   // 8 KB

    const int tid  = threadIdx.x;
    const int lane = tid & 63;
    const int wave = tid >> 6;        // 0..3
    const int wm   = (wave >> 1) * 64;
    const int wn   = (wave & 1) * 64;

    const int bm = blockIdx.x * TM;
    const int bn = blockIdx.y * TN;

    f32x4 acc[4][4] = {};

    // Staging: 8 KB tile = 512 chunks of 16 B. chunk c -> row = c>>2,
    // k-elem-offset = (c&3)*8, LDS byte offset = c*16. Each wave issues 2
    // global_load_lds per tile; lane i lands at (uniform base) + i*16.
    const int c0 = wave * 128 + lane;
    const int c1 = c0 + 64;
    const bf16* gA0 = A + (size_t)(bm + (c0 >> 2)) * K + (c0 & 3) * 8;
    const bf16* gA1 = A + (size_t)(bm + (c1 >> 2)) * K + (c1 & 3) * 8;
    const bf16* gB0 = B + (size_t)(bn + (c0 >> 2)) * K + (c0 & 3) * 8;
    const bf16* gB1 = B + (size_t)(bn + (c1 >> 2)) * K + (c1 & 3) * 8;
    bf16* lA0 = As + (size_t)(wave * 128) * 8;   // chunk-base * 8 elems (16 B)
    bf16* lA1 = lA0 + 64 * 8;
    bf16* lB0 = Bs + (size_t)(wave * 128) * 8;
    bf16* lB1 = lB0 + 64 * 8;

    const int fr = lane & 15;          // row within 16-tile (A: m, B: n)
    const int fk = (lane >> 4) * 8;    // k offset of this lane's 8 elems

    for (int k0 = 0; k0 < K; k0 += BK) {
        __builtin_amdgcn_global_load_lds(
            (const __attribute__((address_space(1))) void*)(gA0 + k0),
            (__attribute__((address_space(3))) void*)lA0, 16, 0, 0);
        __builtin_amdgcn_global_load_lds(
            (const __attribute__((address_space(1))) void*)(gA1 + k0),
            (__attribute__((address_space(3))) void*)lA1, 16, 0, 0);
        __builtin_amdgcn_global_load_lds(
            (const __attribute__((address_space(1))) void*)(gB0 + k0),
            (__attribute__((address_space(3))) void*)lB0, 16, 0, 0);
        __builtin_amdgcn_global_load_lds(
            (const __attribute__((address_space(1))) void*)(gB1 + k0),
            (__attribute__((address_space(3))) void*)lB1, 16, 0, 0);
        __syncthreads();

        bf16x8 af[4], bg[4];
        #pragma unroll
        for (int t = 0; t < 4; ++t) {
            af[t] = *(const bf16x8*)(As + (wm + t * 16 + fr) * BK + fk);
            bg[t] = *(const bf16x8*)(Bs + (wn + t * 16 + fr) * BK + fk);
        }
        #pragma unroll
        for (int i = 0; i < 4; ++i)
            #pragma unroll
            for (int j = 0; j < 4; ++j)
                acc[i][j] = __builtin_amdgcn_mfma_f32_16x16x32_bf16(
                    af[i], bg[j], acc[i][j], 0, 0, 0);
        __syncthreads();
    }

    // C/D layout (m89-verified): col = lane&15, row = (lane>>4)*4 + reg
    const int quad = lane >> 4;
    #pragma unroll
    for (int j = 0; j < 4; ++j) {
        const int col = bn + wn + j * 16 + fr;
        const float bb = bias ? bias[col] : 0.0f;
        #pragma unroll
        for (int i = 0; i < 4; ++i) {
            const int row0 = bm + wm + i * 16 + quad * 4;
            #pragma unroll
            for (int r = 0; r < 4; ++r) {
                const float v = acc[i][j][r] + bb;
                const size_t idx = (size_t)(row0 + r) * N + col;
                C0[idx] = v;
                if (C1) C1[idx] = v;
                if (Cb) Cb[idx] = __float2bfloat16(v);
            }
        }
    }
}

// ---------------- fp32 fallback (no workspace needed) ----------------
__global__ __launch_bounds__(256) void gemm_f32_naive(
    const float* __restrict__ A, const float* __restrict__ B,
    const float* __restrict__ bias,
    float* __restrict__ C0, float* __restrict__ C1,
    int M, int N, int K)
{
    const size_t idx = (size_t)blockIdx.x * 256 + threadIdx.x;
    if (idx >= (size_t)M * N) return;
    const int row = (int)(idx / N), col = (int)(idx % N);
    const float* a = A + (size_t)row * K;
    const float* b = B + (size_t)col * K;
    float s = bias ? bias[col] : 0.0f;
    for (int k = 0; k < K; ++k) s += a[k] * b[k];
    C0[idx] = s;
    if (C1) C1[idx] = s;
}

// Math: softmax row-sums are exactly 1, so x=y=z=v (value projection).
//   out1 = out2 = V = value @ Wv^T + bv   (head split/merge is identity)
//   out0 = V @ Wo^T + bo
// Q/K path is numerically dead code.
extern "C" void kernel_launch(void* const* d_in, const int* in_sizes, int n_in,
                              void* d_out, int out_size, void* d_ws, size_t ws_size,
                              hipStream_t stream)
{
    const float* value = (const float*)d_in[2];
    const float* Wv    = (const float*)d_in[7];
    const float* bv    = (const float*)d_in[8];
    const float* Wo    = (const float*)d_in[9];
    const float* bo    = (const float*)d_in[10];

    const int dm = in_sizes[8];              // 1024 (bv length)
    const int M  = in_sizes[2] / dm;         // 4096 = b*n
    const size_t MN = (size_t)M * dm;

    float* out0 = (float*)d_out;
    float* out1 = out0 + MN;
    float* out2 = out1 + MN;

    const size_t need = MN * 2 + (size_t)dm * dm * 4 + MN * 2; // value_b, Wv_b+Wo_b, V_b
    if (ws_size >= need && (M % TM) == 0 && (dm % TN) == 0 && (dm % BK) == 0) {
        char* ws = (char*)d_ws;
        bf16* value_b = (bf16*)ws;
        bf16* Wv_b    = (bf16*)(ws + MN * 2);
        bf16* Wo_b    = (bf16*)(ws + MN * 2 + (size_t)dm * dm * 2);
        bf16* V_b     = (bf16*)(ws + MN * 2 + (size_t)dm * dm * 4);

        cast4_kernel<<<(int)(MN / 1024), 256, 0, stream>>>(value, value_b);
        cast4_kernel<<<dm * dm / 1024, 256, 0, stream>>>(Wv, Wv_b);
        cast4_kernel<<<dm * dm / 1024, 256, 0, stream>>>(Wo, Wo_b);

        dim3 grid(M / TM, dm / TN);
        // GEMM1: V = value @ Wv^T + bv  -> out1 (fp32), out2 (fp32), V_b (bf16)
        gemm_bt<<<grid, 256, 0, stream>>>(value_b, Wv_b, bv, out1, out2, V_b, M, dm, dm);
        // GEMM2: out0 = V @ Wo^T + bo
        gemm_bt<<<grid, 256, 0, stream>>>(V_b, Wo_b, bo, out0, nullptr, nullptr, M, dm, dm);
    } else {
        const int nblk = (int)((MN + 255) / 256);
        gemm_f32_naive<<<nblk, 256, 0, stream>>>(value, Wv, bv, out1, out2, M, dm, dm);
        gemm_f32_naive<<<nblk, 256, 0, stream>>>(out1, Wo, bo, out0, nullptr, M, dm, dm);
    }
}

// Round 2
// 165.167 us; speedup vs baseline: 1.0780x; 1.0780x over previous
//
#include <hip/hip_runtime.h>
#include <hip/hip_bf16.h>
#include <stdint.h>

using bf16 = __hip_bfloat16;
typedef __attribute__((ext_vector_type(8))) __bf16 bf16x8;
typedef __attribute__((ext_vector_type(4))) float f32x4;

static __device__ __forceinline__ bf16 f2b(float x) { return __float2bfloat16(x); }

// =====================================================================
// Prep kernel: one dispatch does
//   [0, nbVal)                 : value fp32 -> bf16   (4 elems/thread)
//   [nbVal, +nbW)              : Wo    fp32 -> bf16
//   [.., +nbT)                 : Wv 32x32 tile -> Wv_b (straight) + WvT_b (transposed)
//   [.., +dm)                  : bc[i] = dot(Wo[i,:], bv) + bo[i]
// All branches are block-uniform.
// =====================================================================
__global__ __launch_bounds__(256) void prep_kernel(
    const float* __restrict__ value, const float* __restrict__ Wv,
    const float* __restrict__ Wo, const float* __restrict__ bv,
    const float* __restrict__ bo,
    bf16* __restrict__ value_b, bf16* __restrict__ Wv_b,
    bf16* __restrict__ Wo_b, bf16* __restrict__ WvT_b,
    float* __restrict__ bc,
    int nbVal, int nbW, int nbT, int dm)
{
    const int b = blockIdx.x;
    const int tid = threadIdx.x;

    if (b < nbVal) {                       // ---- value cast
        const size_t i = ((size_t)b * 256 + tid) * 4;
        const float4 v = *(const float4*)(value + i);
        bf16 h0 = f2b(v.x), h1 = f2b(v.y), h2 = f2b(v.z), h3 = f2b(v.w);
        uint2 u;
        u.x = (uint32_t)(*(const uint16_t*)&h0) | ((uint32_t)(*(const uint16_t*)&h1) << 16);
        u.y = (uint32_t)(*(const uint16_t*)&h2) | ((uint32_t)(*(const uint16_t*)&h3) << 16);
        *(uint2*)(value_b + i) = u;
    } else if (b < nbVal + nbW) {          // ---- Wo cast
        const size_t i = ((size_t)(b - nbVal) * 256 + tid) * 4;
        const float4 v = *(const float4*)(Wo + i);
        bf16 h0 = f2b(v.x), h1 = f2b(v.y), h2 = f2b(v.z), h3 = f2b(v.w);
        uint2 u;
        u.x = (uint32_t)(*(const uint16_t*)&h0) | ((uint32_t)(*(const uint16_t*)&h1) << 16);
        u.y = (uint32_t)(*(const uint16_t*)&h2) | ((uint32_t)(*(const uint16_t*)&h3) << 16);
        *(uint2*)(Wo_b + i) = u;
    } else if (b < nbVal + nbW + nbT) {    // ---- Wv cast + transpose (32x32 tile)
        __shared__ bf16 tile[32][33];
        const int t = b - nbVal - nbW;
        const int tpr = dm / 32;
        const int i0 = (t / tpr) * 32, j0 = (t % tpr) * 32;
        const int tx = tid & 31, ty = tid >> 5;       // ty in 0..7
        #pragma unroll
        for (int p = 0; p < 4; ++p) {
            const int r = ty + p * 8;
            const float v = Wv[(size_t)(i0 + r) * dm + j0 + tx];
            const bf16 h = f2b(v);
            Wv_b[(size_t)(i0 + r) * dm + j0 + tx] = h;   // straight copy
            tile[r][tx] = h;
        }
        __syncthreads();
        #pragma unroll
        for (int p = 0; p < 4; ++p) {
            const int c = ty + p * 8;
            WvT_b[(size_t)(j0 + c) * dm + i0 + tx] = tile[tx][c];
        }
    } else {                               // ---- bc[i] = Wo[i,:].bv + bo[i]
        __shared__ float red[4];
        const int row = b - nbVal - nbW - nbT;
        const float* wrow = Wo + (size_t)row * dm;
        float s = 0.f;
        for (int k = tid; k < dm; k += 256) s += wrow[k] * bv[k];
        #pragma unroll
        for (int off = 32; off >= 1; off >>= 1) s += __shfl_down(s, off, 64);
        if ((tid & 63) == 0) red[tid >> 6] = s;
        __syncthreads();
        if (tid == 0) bc[row] = red[0] + red[1] + red[2] + red[3] + bo[row];
    }
}

// =====================================================================
// 64x64-tile GEMM: Wc = Wo @ Wv  (via A=Wo_b, B=WvT_b; C[m,n]=sum A[m,k]B[n,k])
// Output bf16 only. grid (M/64, N/64), 256 threads.
// =====================================================================
__global__ __launch_bounds__(256) void gemm64_bt_b16out(
    const bf16* __restrict__ A, const bf16* __restrict__ B,
    bf16* __restrict__ C, int M, int N, int K)
{
    __shared__ bf16 As[64 * 32];   // 4 KB
    __shared__ bf16 Bs[64 * 32];

    const int tid = threadIdx.x;
    const int lane = tid & 63;
    const int wave = tid >> 6;
    const int wm = (wave >> 1) * 32;
    const int wn = (wave & 1) * 32;
    const int bm = blockIdx.x * 64;
    const int bn = blockIdx.y * 64;

    f32x4 acc[2][2] = {};

    const int c = wave * 64 + lane;            // 0..255 chunks of 16 B
    const bf16* gA = A + (size_t)(bm + (c >> 2)) * K + (c & 3) * 8;
    const bf16* gB = B + (size_t)(bn + (c >> 2)) * K + (c & 3) * 8;
    bf16* lA = As + (size_t)c * 8;
    bf16* lB = Bs + (size_t)c * 8;

    const int fr = lane & 15;
    const int fk = (lane >> 4) * 8;

    for (int k0 = 0; k0 < K; k0 += 32) {
        __builtin_amdgcn_global_load_lds(
            (const __attribute__((address_space(1))) void*)(gA + k0),
            (__attribute__((address_space(3))) void*)lA, 16, 0, 0);
        __builtin_amdgcn_global_load_lds(
            (const __attribute__((address_space(1))) void*)(gB + k0),
            (__attribute__((address_space(3))) void*)lB, 16, 0, 0);
        __syncthreads();
        bf16x8 af[2], bg[2];
        #pragma unroll
        for (int t = 0; t < 2; ++t) {
            af[t] = *(const bf16x8*)(As + (wm + t * 16 + fr) * 32 + fk);
            bg[t] = *(const bf16x8*)(Bs + (wn + t * 16 + fr) * 32 + fk);
        }
        #pragma unroll
        for (int i = 0; i < 2; ++i)
            #pragma unroll
            for (int j = 0; j < 2; ++j)
                acc[i][j] = __builtin_amdgcn_mfma_f32_16x16x32_bf16(
                    af[i], bg[j], acc[i][j], 0, 0, 0);
        __syncthreads();
    }

    const int quad = lane >> 4;
    #pragma unroll
    for (int j = 0; j < 2; ++j) {
        const int col = bn + wn + j * 16 + fr;
        #pragma unroll
        for (int i = 0; i < 2; ++i) {
            const int row0 = bm + wm + i * 16 + quad * 4;
            #pragma unroll
            for (int r = 0; r < 4; ++r)
                C[(size_t)(row0 + r) * N + col] = f2b(acc[i][j][r]);
        }
    }
}

// =====================================================================
// Big fused GEMM: C = value_b @ Bcat^T, Bcat = [Wv_b ; Wc_b]  (2*dm x dm).
// grid (M/128, 2*dm/128). Blocks with bn < dm write out1 AND out2 (+bv);
// blocks with bn >= dm write out0 (+bc). m97 structure.
// =====================================================================
#define TM 128
#define TN 128
#define BK 32

__global__ __launch_bounds__(256) void gemm_fused(
    const bf16* __restrict__ A, const bf16* __restrict__ Bcat,
    const float* __restrict__ bv, const float* __restrict__ bc,
    float* __restrict__ out0, float* __restrict__ out1, float* __restrict__ out2,
    int M, int dm)
{
    __shared__ bf16 As[TM * BK];   // 8 KB
    __shared__ bf16 Bs[TN * BK];

    const int K = dm;
    const int tid = threadIdx.x;
    const int lane = tid & 63;
    const int wave = tid >> 6;
    const int wm = (wave >> 1) * 64;
    const int wn = (wave & 1) * 64;
    const int bm = blockIdx.x * TM;
    const int bn = blockIdx.y * TN;

    f32x4 acc[4][4] = {};

    const int c0 = wave * 128 + lane;
    const int c1 = c0 + 64;
    const bf16* gA0 = A + (size_t)(bm + (c0 >> 2)) * K + (c0 & 3) * 8;
    const bf16* gA1 = A + (size_t)(bm + (c1 >> 2)) * K + (c1 & 3) * 8;
    const bf16* gB0 = Bcat + (size_t)(bn + (c0 >> 2)) * K + (c0 & 3) * 8;
    const bf16* gB1 = Bcat + (size_t)(bn + (c1 >> 2)) * K + (c1 & 3) * 8;
    bf16* lA0 = As + (size_t)(wave * 128) * 8;
    bf16* lA1 = lA0 + 64 * 8;
    bf16* lB0 = Bs + (size_t)(wave * 128) * 8;
    bf16* lB1 = lB0 + 64 * 8;

    const int fr = lane & 15;
    const int fk = (lane >> 4) * 8;

    for (int k0 = 0; k0 < K; k0 += BK) {
        __builtin_amdgcn_global_load_lds(
            (const __attribute__((address_space(1))) void*)(gA0 + k0),
            (__attribute__((address_space(3))) void*)lA0, 16, 0, 0);
        __builtin_amdgcn_global_load_lds(
            (const __attribute__((address_space(1))) void*)(gA1 + k0),
            (__attribute__((address_space(3))) void*)lA1, 16, 0, 0);
        __builtin_amdgcn_global_load_lds(
            (const __attribute__((address_space(1))) void*)(gB0 + k0),
            (__attribute__((address_space(3))) void*)lB0, 16, 0, 0);
        __builtin_amdgcn_global_load_lds(
            (const __attribute__((address_space(1))) void*)(gB1 + k0),
            (__attribute__((address_space(3))) void*)lB1, 16, 0, 0);
        __syncthreads();

        bf16x8 af[4], bg[4];
        #pragma unroll
        for (int t = 0; t < 4; ++t) {
            af[t] = *(const bf16x8*)(As + (wm + t * 16 + fr) * BK + fk);
            bg[t] = *(const bf16x8*)(Bs + (wn + t * 16 + fr) * BK + fk);
        }
        #pragma unroll
        for (int i = 0; i < 4; ++i)
            #pragma unroll
            for (int j = 0; j < 4; ++j)
                acc[i][j] = __builtin_amdgcn_mfma_f32_16x16x32_bf16(
                    af[i], bg[j], acc[i][j], 0, 0, 0);
        __syncthreads();
    }

    // C/D layout: col = lane&15, row = (lane>>4)*4 + reg  (m89-verified)
    const bool second = (bn >= dm);                 // block-uniform
    const int cb = bn + wn - (second ? dm : 0);
    const float* bias = second ? bc : bv;
    float* o0 = second ? out0 : out1;
    float* o1 = second ? nullptr : out2;
    const int quad = lane >> 4;
    #pragma unroll
    for (int j = 0; j < 4; ++j) {
        const int col = cb + j * 16 + fr;
        const float bb = bias[col];
        #pragma unroll
        for (int i = 0; i < 4; ++i) {
            const int row0 = bm + wm + i * 16 + quad * 4;
            #pragma unroll
            for (int r = 0; r < 4; ++r) {
                const float v = acc[i][j][r] + bb;
                const size_t idx = (size_t)(row0 + r) * dm + col;
                o0[idx] = v;
                if (o1) o1[idx] = v;
            }
        }
    }
}

// ---------------- fp32 fallback (no workspace needed) ----------------
__global__ __launch_bounds__(256) void gemm_f32_naive(
    const float* __restrict__ A, const float* __restrict__ B,
    const float* __restrict__ bias,
    float* __restrict__ C0, float* __restrict__ C1,
    int M, int N, int K)
{
    const size_t idx = (size_t)blockIdx.x * 256 + threadIdx.x;
    if (idx >= (size_t)M * N) return;
    const int row = (int)(idx / N), col = (int)(idx % N);
    const float* a = A + (size_t)row * K;
    const float* b = B + (size_t)col * K;
    float s = bias ? bias[col] : 0.0f;
    for (int k = 0; k < K; ++k) s += a[k] * b[k];
    C0[idx] = s;
    if (C1) C1[idx] = s;
}

// Math: softmax row-sums are exactly 1 => x=y=z=v (value projection).
//   out1 = out2 = V = value @ Wv^T + bv
//   out0 = V @ Wo^T + bo = value @ (Wo@Wv)^T + (Wo@bv + bo)
// Fold: Wc = Wo@Wv, bc = Wo@bv+bo, then ONE big GEMM with Bcat=[Wv;Wc] (N=2dm)
// -> 512 blocks (2/CU) instead of two serial 256-block GEMMs.
extern "C" void kernel_launch(void* const* d_in, const int* in_sizes, int n_in,
                              void* d_out, int out_size, void* d_ws, size_t ws_size,
                              hipStream_t stream)
{
    const float* value = (const float*)d_in[2];
    const float* Wv    = (const float*)d_in[7];
    const float* bv    = (const float*)d_in[8];
    const float* Wo    = (const float*)d_in[9];
    const float* bo    = (const float*)d_in[10];

    const int dm = in_sizes[8];              // 1024
    const int M  = in_sizes[2] / dm;         // 4096
    const size_t MN = (size_t)M * dm;

    float* out0 = (float*)d_out;
    float* out1 = out0 + MN;
    float* out2 = out1 + MN;

    // ws layout: value_b | Wv_b | Wc_b (contiguous pair = Bcat) | Wo_b | WvT_b | bc
    const size_t need = MN * 2 + (size_t)dm * dm * 2 * 4 + (size_t)dm * 4;
    const bool ok = (ws_size >= need) && (M % TM == 0) && (dm % TM == 0) &&
                    (dm % 32 == 0) && (MN % 1024 == 0);
    if (ok) {
        char* ws = (char*)d_ws;
        bf16* value_b = (bf16*)ws;                                   ws += MN * 2;
        bf16* Wv_b    = (bf16*)ws;                                   ws += (size_t)dm * dm * 2;
        bf16* Wc_b    = (bf16*)ws;                                   ws += (size_t)dm * dm * 2;
        bf16* Wo_b    = (bf16*)ws;                                   ws += (size_t)dm * dm * 2;
        bf16* WvT_b   = (bf16*)ws;                                   ws += (size_t)dm * dm * 2;
        float* bc     = (float*)ws;

        const int nbVal = (int)(MN / 1024);
        const int nbW   = dm * dm / 1024;
        const int nbT   = (dm / 32) * (dm / 32);
        prep_kernel<<<nbVal + nbW + nbT + dm, 256, 0, stream>>>(
            value, Wv, Wo, bv, bo, value_b, Wv_b, Wo_b, WvT_b, bc,
            nbVal, nbW, nbT, dm);

        dim3 g64(dm / 64, dm / 64);
        gemm64_bt_b16out<<<g64, 256, 0, stream>>>(Wo_b, WvT_b, Wc_b, dm, dm, dm);

        dim3 grid(M / TM, 2 * dm / TN);
        gemm_fused<<<grid, 256, 0, stream>>>(value_b, Wv_b /* Bcat head */,
                                             bv, bc, out0, out1, out2, M, dm);
    } else {
        const int nblk = (int)((MN + 255) / 256);
        gemm_f32_naive<<<nblk, 256, 0, stream>>>(value, Wv, bv, out1, out2, M, dm, dm);
        gemm_f32_naive<<<nblk, 256, 0, stream>>>(out1, Wo, bo, out0, nullptr, M, dm, dm);
    }
}